// Round 3
// baseline (84.016 us; speedup 1.0000x reference)
//
#include <hip/hip_runtime.h>

#define NBLK 1024
#define SBAT 256
#define SBLK 8

// Phase 1: one THREAD per system (i,b): full 8x8 Gauss-Jordan on [A | B | v]
// in registers, fully unrolled (no shuffles, no LDS). A is diagonally
// dominant -> no pivoting. Produces C_i = A_i^{-1} B_{i-1} (C_0 = 0) and
// d_i = A_i^{-1} v_i.
__global__ __launch_bounds__(256) void pcr_phase1(
    const float* __restrict__ A, const float* __restrict__ B,
    const float* __restrict__ v, float* __restrict__ C, float* __restrict__ D) {
  const int i = blockIdx.x;    // time block (one block of 256 threads per i)
  const int b = threadIdx.x;   // batch
  const long sysid = (long)i * SBAT + b;

  float a[8][8], c[8][8], vv[8];

  {
    const float4* A4 = (const float4*)(A + sysid * 64);
    #pragma unroll
    for (int r = 0; r < 8; ++r) {
      const float4 lo = A4[2 * r], hi = A4[2 * r + 1];
      a[r][0]=lo.x; a[r][1]=lo.y; a[r][2]=lo.z; a[r][3]=lo.w;
      a[r][4]=hi.x; a[r][5]=hi.y; a[r][6]=hi.z; a[r][7]=hi.w;
    }
  }
  {
    const long bsys = (i > 0) ? (sysid - SBAT) : 0;   // block (i-1, b)
    const float4* B4 = (const float4*)(B + bsys * 64);
    #pragma unroll
    for (int r = 0; r < 8; ++r) {
      const float4 lo = B4[2 * r], hi = B4[2 * r + 1];
      c[r][0]=lo.x; c[r][1]=lo.y; c[r][2]=lo.z; c[r][3]=lo.w;
      c[r][4]=hi.x; c[r][5]=hi.y; c[r][6]=hi.z; c[r][7]=hi.w;
    }
    if (i == 0) {
      #pragma unroll
      for (int r = 0; r < 8; ++r)
        #pragma unroll
        for (int j = 0; j < 8; ++j) c[r][j] = 0.f;
    }
  }
  {
    const float4* V4 = (const float4*)(v + (long)b * (NBLK * SBLK) + i * SBLK);
    const float4 lo = V4[0], hi = V4[1];
    vv[0]=lo.x; vv[1]=lo.y; vv[2]=lo.z; vv[3]=lo.w;
    vv[4]=hi.x; vv[5]=hi.y; vv[6]=hi.z; vv[7]=hi.w;
  }

  // Gauss-Jordan full reduce: a -> I (tracking only columns > k; columns
  // <= k are identity and never read again), c -> A^{-1}B, vv -> A^{-1}v.
  #pragma unroll
  for (int k = 0; k < 8; ++k) {
    const float invp = 1.0f / a[k][k];
    #pragma unroll
    for (int j = k + 1; j < 8; ++j) a[k][j] *= invp;
    #pragma unroll
    for (int j = 0; j < 8; ++j) c[k][j] *= invp;
    vv[k] *= invp;
    #pragma unroll
    for (int r = 0; r < 8; ++r) {
      if (r == k) continue;
      const float f = a[r][k];
      #pragma unroll
      for (int j = k + 1; j < 8; ++j) a[r][j] = fmaf(-f, a[k][j], a[r][j]);
      #pragma unroll
      for (int j = 0; j < 8; ++j) c[r][j] = fmaf(-f, c[k][j], c[r][j]);
      vv[r] = fmaf(-f, vv[k], vv[r]);
    }
  }

  {
    float4* C4 = (float4*)(C + sysid * 64);
    #pragma unroll
    for (int r = 0; r < 8; ++r) {
      C4[2 * r]     = make_float4(c[r][0], c[r][1], c[r][2], c[r][3]);
      C4[2 * r + 1] = make_float4(c[r][4], c[r][5], c[r][6], c[r][7]);
    }
    float4* D4 = (float4*)(D + sysid * 8);
    D4[0] = make_float4(vv[0], vv[1], vv[2], vv[3]);
    D4[1] = make_float4(vv[4], vv[5], vv[6], vv[7]);
  }
}

// Phase 2: x_i = d_i - C_i x_{i-1}, parallelized over the time axis by
// chunking: NBLK split into chunks of CL; each chunk starts from x=0 at
// (chunk_start - HW) and runs HW warm-up steps. Contraction ||C||~0.1 makes
// the truncation error ~0.1^HW ~ 1e-16 (<< fp32 rounding). 8192 systems,
// 1024 waves. Static double-buffered prefetch (all reg indices const).
#define CL 32
#define CH_N (NBLK / CL)   // 32
#define HW 16              // warm-up steps
#define NB 8               // prefetch group size

__global__ __launch_bounds__(256) void pcr_phase2(
    const float* __restrict__ C, const float* __restrict__ D,
    float* __restrict__ out) {
  const int r = threadIdx.x & 7;
  const int g = blockIdx.x * 32 + (threadIdx.x >> 3);  // global system id
  const int b = g & (SBAT - 1);
  const int c = g >> 8;                                 // chunk id
  const int i_out   = c * CL;
  const int i_first = (c > 0) ? (i_out - HW) : 0;
  const int niter   = CL + ((c > 0) ? HW : 0);          // 48 or 32 (mult of 16)
  const int i_last  = i_out + CL - 1;

  const float4* C4 = (const float4*)C;

  float4 al[NB], ah[NB]; float ad[NB];
  float4 bl[NB], bh[NB]; float bd[NB];

#define LOADG(Pl, Ph, Pd, BASE)                                         \
  {                                                                     \
    _Pragma("unroll")                                                   \
    for (int j = 0; j < NB; ++j) {                                      \
      int ii = i_first + (BASE) + j;                                    \
      ii = (ii > i_last) ? i_last : ii;                                 \
      const long cb = (((long)ii * SBAT + b) * 8 + r) * 2;              \
      Pl[j] = C4[cb]; Ph[j] = C4[cb + 1];                               \
      Pd[j] = D[((long)ii * SBAT + b) * 8 + r];                         \
    }                                                                   \
  }

#define CONSUME(Pl, Ph, Pd, BASE)                                       \
  {                                                                     \
    _Pragma("unroll")                                                   \
    for (int j = 0; j < NB; ++j) {                                      \
      const int i = i_first + (BASE) + j;                               \
      const float4 cl = Pl[j], ch = Ph[j];                              \
      const float dd = Pd[j];                                           \
      const float x0=__shfl(xprev,0,8), x1=__shfl(xprev,1,8),           \
                  x2=__shfl(xprev,2,8), x3=__shfl(xprev,3,8),           \
                  x4=__shfl(xprev,4,8), x5=__shfl(xprev,5,8),           \
                  x6=__shfl(xprev,6,8), x7=__shfl(xprev,7,8);           \
      float acc0 = cl.x * x0;                                           \
      acc0 = fmaf(cl.z, x2, acc0);                                      \
      acc0 = fmaf(ch.x, x4, acc0);                                      \
      acc0 = fmaf(ch.z, x6, acc0);                                      \
      float acc1 = cl.y * x1;                                           \
      acc1 = fmaf(cl.w, x3, acc1);                                      \
      acc1 = fmaf(ch.y, x5, acc1);                                      \
      acc1 = fmaf(ch.w, x7, acc1);                                      \
      const float x = dd - acc0 - acc1;                                 \
      if (i >= i_out) out[(long)b * (NBLK * SBLK) + i * SBLK + r] = x;  \
      xprev = x;                                                        \
    }                                                                   \
  }

  float xprev = 0.f;
  LOADG(al, ah, ad, 0);
  for (int t = 0; t < niter; t += 2 * NB) {
    LOADG(bl, bh, bd, t + NB);
    CONSUME(al, ah, ad, t);
    LOADG(al, ah, ad, t + 2 * NB);
    CONSUME(bl, bh, bd, t + NB);
  }
}

extern "C" void kernel_launch(void* const* d_in, const int* in_sizes, int n_in,
                              void* d_out, int out_size, void* d_ws, size_t ws_size,
                              hipStream_t stream) {
  const float* A = (const float*)d_in[0];
  const float* B = (const float*)d_in[1];
  const float* v = (const float*)d_in[2];
  float* C = (float*)d_ws;                                          // 64 MiB
  float* D = (float*)((char*)d_ws + (size_t)NBLK*SBAT*SBLK*SBLK*4); // +8 MiB
  float* out = (float*)d_out;

  pcr_phase1<<<NBLK, 256, 0, stream>>>(A, B, v, C, D);
  pcr_phase2<<<(CH_N * SBAT) / 32, 256, 0, stream>>>(C, D, out);
}

// Round 4
// 66.696 us; speedup vs baseline: 1.2597x; 1.2597x over previous
//
#include <hip/hip_runtime.h>

#define NBLK 1024
#define SBAT 256
#define SBLK 8

// Broadcast within lane PAIRS via DPP quad_perm (VALU pipe, no DS ops).
__device__ __forceinline__ float bc_lo(float x) {  // take even lane of pair
  return __int_as_float(__builtin_amdgcn_update_dpp(
      0, __float_as_int(x), 0xA0, 0xF, 0xF, true));  // quad_perm [0,0,2,2]
}
__device__ __forceinline__ float bc_hi(float x) {  // take odd lane of pair
  return __int_as_float(__builtin_amdgcn_update_dpp(
      0, __float_as_int(x), 0xF5, 0xF, 0xF, true));  // quad_perm [1,1,3,3]
}

// Phase 1: 2 lanes per system (lane half h owns rows h*4..h*4+3 of [A|C|v]).
// Gauss-Jordan on [A | B_{i-1} | v] -> C_i = A^{-1}B, d_i = A^{-1}v.
// Pivot-row broadcast via DPP pair-broadcast: zero DS traffic, no spills
// (68 data floats/lane). A diagonally dominant -> no pivoting.
__global__ __launch_bounds__(256) void pcr_phase1(
    const float* __restrict__ A, const float* __restrict__ B,
    const float* __restrict__ v, float* __restrict__ C, float* __restrict__ D) {
  const int tid  = threadIdx.x;
  const int lane = tid & 63;
  const int wib  = tid >> 6;
  const int p = lane >> 1;                      // system within wave (0..31)
  const int h = lane & 1;                       // row-half (0: rows 0-3)
  const long w  = (long)blockIdx.x * 4 + wib;
  const long t0 = w * 32;
  const int i = (int)(t0 >> 8);                 // time block
  const int b = (int)(t0 & 255) + p;            // batch
  const long sysid = (long)i * SBAT + b;

  float a[4][8], c[4][8], vv[4];

  {
    const float4* A4 = (const float4*)(A + sysid * 64 + h * 32);
    #pragma unroll
    for (int lr = 0; lr < 4; ++lr) {
      const float4 lo = A4[2 * lr], hi = A4[2 * lr + 1];
      a[lr][0]=lo.x; a[lr][1]=lo.y; a[lr][2]=lo.z; a[lr][3]=lo.w;
      a[lr][4]=hi.x; a[lr][5]=hi.y; a[lr][6]=hi.z; a[lr][7]=hi.w;
    }
  }
  if (i > 0) {   // wave-uniform branch (whole wave shares one i)
    const float4* B4 = (const float4*)(B + (sysid - SBAT) * 64 + h * 32);
    #pragma unroll
    for (int lr = 0; lr < 4; ++lr) {
      const float4 lo = B4[2 * lr], hi = B4[2 * lr + 1];
      c[lr][0]=lo.x; c[lr][1]=lo.y; c[lr][2]=lo.z; c[lr][3]=lo.w;
      c[lr][4]=hi.x; c[lr][5]=hi.y; c[lr][6]=hi.z; c[lr][7]=hi.w;
    }
  } else {
    #pragma unroll
    for (int lr = 0; lr < 4; ++lr)
      #pragma unroll
      for (int j = 0; j < 8; ++j) c[lr][j] = 0.f;
  }
  {
    const float4 t = *(const float4*)(v + (long)b * (NBLK * SBLK) + i * SBLK + h * 4);
    vv[0]=t.x; vv[1]=t.y; vv[2]=t.z; vv[3]=t.w;
  }

  // Gauss-Jordan, fully unrolled; K is a literal so all indices are static.
#define GJSTEP(K, BC)                                                   \
  {                                                                     \
    constexpr int kr = (K) & 3;                                         \
    const bool mine = (h == ((K) >> 2));                                \
    const float invp = 1.0f / a[kr][(K)];                               \
    const float s = mine ? invp : 1.0f;                                 \
    _Pragma("unroll")                                                   \
    for (int j = (K) + 1; j < 8; ++j) a[kr][j] *= s;                    \
    _Pragma("unroll")                                                   \
    for (int j = 0; j < 8; ++j) c[kr][j] *= s;                          \
    vv[kr] *= s;                                                        \
    float pa[8], pc[8], pv;                                             \
    _Pragma("unroll")                                                   \
    for (int j = (K) + 1; j < 8; ++j) pa[j] = BC(a[kr][j]);             \
    _Pragma("unroll")                                                   \
    for (int j = 0; j < 8; ++j) pc[j] = BC(c[kr][j]);                   \
    pv = BC(vv[kr]);                                                    \
    _Pragma("unroll")                                                   \
    for (int lr = 0; lr < 4; ++lr) {                                    \
      float f = a[lr][(K)];                                             \
      if (lr == kr) f = mine ? 0.0f : f;                                \
      _Pragma("unroll")                                                 \
      for (int j = (K) + 1; j < 8; ++j)                                 \
        a[lr][j] = fmaf(-f, pa[j], a[lr][j]);                           \
      _Pragma("unroll")                                                 \
      for (int j = 0; j < 8; ++j)                                       \
        c[lr][j] = fmaf(-f, pc[j], c[lr][j]);                           \
      vv[lr] = fmaf(-f, pv, vv[lr]);                                    \
    }                                                                   \
  }

  GJSTEP(0, bc_lo) GJSTEP(1, bc_lo) GJSTEP(2, bc_lo) GJSTEP(3, bc_lo)
  GJSTEP(4, bc_hi) GJSTEP(5, bc_hi) GJSTEP(6, bc_hi) GJSTEP(7, bc_hi)
#undef GJSTEP

  {
    float4* C4 = (float4*)(C + sysid * 64 + h * 32);
    #pragma unroll
    for (int lr = 0; lr < 4; ++lr) {
      C4[2 * lr]     = make_float4(c[lr][0], c[lr][1], c[lr][2], c[lr][3]);
      C4[2 * lr + 1] = make_float4(c[lr][4], c[lr][5], c[lr][6], c[lr][7]);
    }
    *(float4*)(D + sysid * 8 + h * 4) = make_float4(vv[0], vv[1], vv[2], vv[3]);
  }
}

// Phase 2: x_i = d_i - C_i x_{i-1}, parallelized over the time axis by
// chunking with HW warm-up steps from x=0 (contraction ||C||~0.1 ->
// truncation ~0.1^HW, far below fp32 rounding). 8192 systems, 1024 waves.
#define CL 32
#define CH_N (NBLK / CL)   // 32
#define HW 16              // warm-up steps
#define NB 8               // prefetch group size

__global__ __launch_bounds__(256) void pcr_phase2(
    const float* __restrict__ C, const float* __restrict__ D,
    float* __restrict__ out) {
  const int r = threadIdx.x & 7;
  const int g = blockIdx.x * 32 + (threadIdx.x >> 3);  // global system id
  const int b = g & (SBAT - 1);
  const int c = g >> 8;                                 // chunk id
  const int i_out   = c * CL;
  const int i_first = (c > 0) ? (i_out - HW) : 0;
  const int niter   = CL + ((c > 0) ? HW : 0);          // 48 or 32 (mult of 16)
  const int i_last  = i_out + CL - 1;

  const float4* C4 = (const float4*)C;

  float4 al[NB], ah[NB]; float ad[NB];
  float4 bl[NB], bh[NB]; float bd[NB];

#define LOADG(Pl, Ph, Pd, BASE)                                         \
  {                                                                     \
    _Pragma("unroll")                                                   \
    for (int j = 0; j < NB; ++j) {                                      \
      int ii = i_first + (BASE) + j;                                    \
      ii = (ii > i_last) ? i_last : ii;                                 \
      const long cb = (((long)ii * SBAT + b) * 8 + r) * 2;              \
      Pl[j] = C4[cb]; Ph[j] = C4[cb + 1];                               \
      Pd[j] = D[((long)ii * SBAT + b) * 8 + r];                         \
    }                                                                   \
  }

#define CONSUME(Pl, Ph, Pd, BASE)                                       \
  {                                                                     \
    _Pragma("unroll")                                                   \
    for (int j = 0; j < NB; ++j) {                                      \
      const int i = i_first + (BASE) + j;                               \
      const float4 cl = Pl[j], ch = Ph[j];                              \
      const float dd = Pd[j];                                           \
      const float x0=__shfl(xprev,0,8), x1=__shfl(xprev,1,8),           \
                  x2=__shfl(xprev,2,8), x3=__shfl(xprev,3,8),           \
                  x4=__shfl(xprev,4,8), x5=__shfl(xprev,5,8),           \
                  x6=__shfl(xprev,6,8), x7=__shfl(xprev,7,8);           \
      float acc0 = cl.x * x0;                                           \
      acc0 = fmaf(cl.z, x2, acc0);                                      \
      acc0 = fmaf(ch.x, x4, acc0);                                      \
      acc0 = fmaf(ch.z, x6, acc0);                                      \
      float acc1 = cl.y * x1;                                           \
      acc1 = fmaf(cl.w, x3, acc1);                                      \
      acc1 = fmaf(ch.y, x5, acc1);                                      \
      acc1 = fmaf(ch.w, x7, acc1);                                      \
      const float x = dd - acc0 - acc1;                                 \
      if (i >= i_out) out[(long)b * (NBLK * SBLK) + i * SBLK + r] = x;  \
      xprev = x;                                                        \
    }                                                                   \
  }

  float xprev = 0.f;
  LOADG(al, ah, ad, 0);
  for (int t = 0; t < niter; t += 2 * NB) {
    LOADG(bl, bh, bd, t + NB);
    CONSUME(al, ah, ad, t);
    LOADG(al, ah, ad, t + 2 * NB);
    CONSUME(bl, bh, bd, t + NB);
  }
}

extern "C" void kernel_launch(void* const* d_in, const int* in_sizes, int n_in,
                              void* d_out, int out_size, void* d_ws, size_t ws_size,
                              hipStream_t stream) {
  const float* A = (const float*)d_in[0];
  const float* B = (const float*)d_in[1];
  const float* v = (const float*)d_in[2];
  float* C = (float*)d_ws;                                          // 64 MiB
  float* D = (float*)((char*)d_ws + (size_t)NBLK*SBAT*SBLK*SBLK*4); // +8 MiB
  float* out = (float*)d_out;

  pcr_phase1<<<(NBLK * SBAT) / 128, 256, 0, stream>>>(A, B, v, C, D);
  pcr_phase2<<<(CH_N * SBAT) / 32, 256, 0, stream>>>(C, D, out);
}

// Round 5
// 58.554 us; speedup vs baseline: 1.4349x; 1.1391x over previous
//
#include <hip/hip_runtime.h>

#define NBLK 1024
#define SBAT 256
#define SBLK 8

#define SPB 64              // systems per phase-1 block
#define THREADS (SPB * 2)   // 2 lanes per system

typedef __attribute__((address_space(3))) void lds_void_t;
typedef const __attribute__((address_space(1))) void glob_void_t;

// Broadcast within lane PAIRS via DPP quad_perm (VALU pipe, no DS ops).
__device__ __forceinline__ float bc_lo(float x) {  // take even lane of pair
  return __int_as_float(__builtin_amdgcn_update_dpp(
      0, __float_as_int(x), 0xA0, 0xF, 0xF, true));  // quad_perm [0,0,2,2]
}
__device__ __forceinline__ float bc_hi(float x) {  // take odd lane of pair
  return __int_as_float(__builtin_amdgcn_update_dpp(
      0, __float_as_int(x), 0xF5, 0xF, 0xF, true));  // quad_perm [1,1,3,3]
}

// Phase 1: 2 lanes per system, DPP Gauss-Jordan on [A | B_{i-1} | v] ->
// C_i = A^{-1}B (C_0=0), d_i = A^{-1}v. All global traffic is
// linearized through LDS:
//   - A,B panels: global_load_lds (1 KB contiguous per wave-inst), source
//     pre-swizzled (XOR bits[6:4] with sys&7) so the per-thread swizzled
//     ds_read_b128 fragments are bank-conflict-free (8 lanes/bank-quad).
//   - C: written back into LDS (swizzled), then linear readback + fully
//     coalesced global stores (store addr = swz(linear), contiguous per inst).
// Each wave stages/reads only its own 8 KB quarter -> no barrier before GJ.
__global__ __launch_bounds__(THREADS) void pcr_phase1(
    const float* __restrict__ A, const float* __restrict__ B,
    const float* __restrict__ v, float* __restrict__ C, float* __restrict__ D) {
  __shared__ float ldsA[SPB * 64];   // 16 KB, reused for C bounce
  __shared__ float ldsB[SPB * 64];   // 16 KB

  const int tid  = threadIdx.x;
  const int lane = tid & 63;
  const int w    = tid >> 6;                   // wave in block (0..1)
  const int p = lane >> 1, h = lane & 1;       // system-in-wave, row-half
  const int i  = blockIdx.x >> 2;              // time block
  const int b0 = (blockIdx.x & 3) * SPB;       // batch panel origin
  const int sys_local = w * 32 + p;            // 0..63
  const int b = b0 + sys_local;
  const long sysid = (long)i * SBAT + b;

  {  // stage A panel (16 KB): wave w loads its own 8 KB quarter
    const char* Ag = (const char*)(A + ((long)i * SBAT + b0) * 64);
    #pragma unroll
    for (int k = 0; k < 8; ++k) {
      const int o  = w * 8192 + k * 1024 + lane * 16;
      const int os = o ^ (((o >> 8) & 7) << 4);
      __builtin_amdgcn_global_load_lds(
          (glob_void_t*)(Ag + os),
          (lds_void_t*)((char*)ldsA + w * 8192 + k * 1024), 16, 0, 0);
    }
  }
  if (i > 0) {  // wave-uniform branch
    const char* Bg = (const char*)(B + ((long)(i - 1) * SBAT + b0) * 64);
    #pragma unroll
    for (int k = 0; k < 8; ++k) {
      const int o  = w * 8192 + k * 1024 + lane * 16;
      const int os = o ^ (((o >> 8) & 7) << 4);
      __builtin_amdgcn_global_load_lds(
          (glob_void_t*)(Bg + os),
          (lds_void_t*)((char*)ldsB + w * 8192 + k * 1024), 16, 0, 0);
    }
  }

  float vv[4];
  {
    const float4 t = *(const float4*)(v + (long)b * (NBLK * SBLK) + i * SBLK + h * 4);
    vv[0]=t.x; vv[1]=t.y; vv[2]=t.z; vv[3]=t.w;
  }

  asm volatile("s_waitcnt vmcnt(0)" ::: "memory");

  float a[4][8], c[4][8];
  const int swz = (p & 7) << 4;
  {
    const char* base = (const char*)ldsA + sys_local * 256 + h * 128;
    #pragma unroll
    for (int q = 0; q < 8; ++q) {
      const float4 t = *(const float4*)(base + ((q * 16) ^ swz));
      const int lr = q >> 1, c0 = (q & 1) * 4;
      a[lr][c0+0]=t.x; a[lr][c0+1]=t.y; a[lr][c0+2]=t.z; a[lr][c0+3]=t.w;
    }
  }
  if (i > 0) {
    const char* base = (const char*)ldsB + sys_local * 256 + h * 128;
    #pragma unroll
    for (int q = 0; q < 8; ++q) {
      const float4 t = *(const float4*)(base + ((q * 16) ^ swz));
      const int lr = q >> 1, c0 = (q & 1) * 4;
      c[lr][c0+0]=t.x; c[lr][c0+1]=t.y; c[lr][c0+2]=t.z; c[lr][c0+3]=t.w;
    }
  } else {
    #pragma unroll
    for (int lr = 0; lr < 4; ++lr)
      #pragma unroll
      for (int j = 0; j < 8; ++j) c[lr][j] = 0.f;
  }

  // Gauss-Jordan, fully unrolled; K literal -> all register indices static.
#define GJSTEP(K, BC)                                                   \
  {                                                                     \
    constexpr int kr = (K) & 3;                                         \
    const bool mine = (h == ((K) >> 2));                                \
    const float invp = 1.0f / a[kr][(K)];                               \
    const float s = mine ? invp : 1.0f;                                 \
    _Pragma("unroll")                                                   \
    for (int j = (K) + 1; j < 8; ++j) a[kr][j] *= s;                    \
    _Pragma("unroll")                                                   \
    for (int j = 0; j < 8; ++j) c[kr][j] *= s;                          \
    vv[kr] *= s;                                                        \
    float pa[8], pc[8], pv;                                             \
    _Pragma("unroll")                                                   \
    for (int j = (K) + 1; j < 8; ++j) pa[j] = BC(a[kr][j]);             \
    _Pragma("unroll")                                                   \
    for (int j = 0; j < 8; ++j) pc[j] = BC(c[kr][j]);                   \
    pv = BC(vv[kr]);                                                    \
    _Pragma("unroll")                                                   \
    for (int lr = 0; lr < 4; ++lr) {                                    \
      float f = a[lr][(K)];                                             \
      if (lr == kr) f = mine ? 0.0f : f;                                \
      _Pragma("unroll")                                                 \
      for (int j = (K) + 1; j < 8; ++j)                                 \
        a[lr][j] = fmaf(-f, pa[j], a[lr][j]);                           \
      _Pragma("unroll")                                                 \
      for (int j = 0; j < 8; ++j)                                       \
        c[lr][j] = fmaf(-f, pc[j], c[lr][j]);                           \
      vv[lr] = fmaf(-f, pv, vv[lr]);                                    \
    }                                                                   \
  }

  GJSTEP(0, bc_lo) GJSTEP(1, bc_lo) GJSTEP(2, bc_lo) GJSTEP(3, bc_lo)
  GJSTEP(4, bc_hi) GJSTEP(5, bc_hi) GJSTEP(6, bc_hi) GJSTEP(7, bc_hi)
#undef GJSTEP

  {  // C -> LDS (swizzled, conflict-free; own quarter only)
    char* cb = (char*)ldsA + sys_local * 256 + h * 128;
    #pragma unroll
    for (int q = 0; q < 8; ++q) {
      const int lr = q >> 1, c0 = (q & 1) * 4;
      *(float4*)(cb + ((q * 16) ^ swz)) =
          make_float4(c[lr][c0+0], c[lr][c0+1], c[lr][c0+2], c[lr][c0+3]);
    }
  }
  // D store: lane l writes bytes l*16 within the wave's 1 KB -> coalesced
  *(float4*)(D + sysid * 8 + h * 4) = make_float4(vv[0], vv[1], vv[2], vv[3]);

  __syncthreads();

  {  // linear LDS readback, coalesced global C store (addr = swz(linear))
    char* Cg = (char*)(C + ((long)i * SBAT + b0) * 64);
    #pragma unroll
    for (int k = 0; k < 8; ++k) {
      const int o  = k * 2048 + tid * 16;
      const int os = o ^ (((o >> 8) & 7) << 4);
      const float4 t = *(const float4*)((const char*)ldsA + o);
      *(float4*)(Cg + os) = t;
    }
  }
}

// Phase 2: x_i = d_i - C_i x_{i-1}, time-parallel via chunking with HW
// warm-up steps from x=0 (contraction ||C||~0.1 -> truncation ~0.1^HW,
// far below fp32 rounding). 8192 systems, 1024 waves.
#define CL 32
#define CH_N (NBLK / CL)   // 32
#define HW 16              // warm-up steps
#define NB 8               // prefetch group size

__global__ __launch_bounds__(256) void pcr_phase2(
    const float* __restrict__ C, const float* __restrict__ D,
    float* __restrict__ out) {
  const int r = threadIdx.x & 7;
  const int g = blockIdx.x * 32 + (threadIdx.x >> 3);  // global system id
  const int b = g & (SBAT - 1);
  const int c = g >> 8;                                 // chunk id
  const int i_out   = c * CL;
  const int i_first = (c > 0) ? (i_out - HW) : 0;
  const int niter   = CL + ((c > 0) ? HW : 0);          // 48 or 32 (mult of 16)
  const int i_last  = i_out + CL - 1;

  const float4* C4 = (const float4*)C;

  float4 al[NB], ah[NB]; float ad[NB];
  float4 bl[NB], bh[NB]; float bd[NB];

#define LOADG(Pl, Ph, Pd, BASE)                                         \
  {                                                                     \
    _Pragma("unroll")                                                   \
    for (int j = 0; j < NB; ++j) {                                      \
      int ii = i_first + (BASE) + j;                                    \
      ii = (ii > i_last) ? i_last : ii;                                 \
      const long cb = (((long)ii * SBAT + b) * 8 + r) * 2;              \
      Pl[j] = C4[cb]; Ph[j] = C4[cb + 1];                               \
      Pd[j] = D[((long)ii * SBAT + b) * 8 + r];                         \
    }                                                                   \
  }

#define CONSUME(Pl, Ph, Pd, BASE)                                       \
  {                                                                     \
    _Pragma("unroll")                                                   \
    for (int j = 0; j < NB; ++j) {                                      \
      const int i = i_first + (BASE) + j;                               \
      const float4 cl = Pl[j], ch = Ph[j];                              \
      const float dd = Pd[j];                                           \
      const float x0=__shfl(xprev,0,8), x1=__shfl(xprev,1,8),           \
                  x2=__shfl(xprev,2,8), x3=__shfl(xprev,3,8),           \
                  x4=__shfl(xprev,4,8), x5=__shfl(xprev,5,8),           \
                  x6=__shfl(xprev,6,8), x7=__shfl(xprev,7,8);           \
      float acc0 = cl.x * x0;                                           \
      acc0 = fmaf(cl.z, x2, acc0);                                      \
      acc0 = fmaf(ch.x, x4, acc0);                                      \
      acc0 = fmaf(ch.z, x6, acc0);                                      \
      float acc1 = cl.y * x1;                                           \
      acc1 = fmaf(cl.w, x3, acc1);                                      \
      acc1 = fmaf(ch.y, x5, acc1);                                      \
      acc1 = fmaf(ch.w, x7, acc1);                                      \
      const float x = dd - acc0 - acc1;                                 \
      if (i >= i_out) out[(long)b * (NBLK * SBLK) + i * SBLK + r] = x;  \
      xprev = x;                                                        \
    }                                                                   \
  }

  float xprev = 0.f;
  LOADG(al, ah, ad, 0);
  for (int t = 0; t < niter; t += 2 * NB) {
    LOADG(bl, bh, bd, t + NB);
    CONSUME(al, ah, ad, t);
    LOADG(al, ah, ad, t + 2 * NB);
    CONSUME(bl, bh, bd, t + NB);
  }
}

extern "C" void kernel_launch(void* const* d_in, const int* in_sizes, int n_in,
                              void* d_out, int out_size, void* d_ws, size_t ws_size,
                              hipStream_t stream) {
  const float* A = (const float*)d_in[0];
  const float* B = (const float*)d_in[1];
  const float* v = (const float*)d_in[2];
  float* C = (float*)d_ws;                                          // 64 MiB
  float* D = (float*)((char*)d_ws + (size_t)NBLK*SBAT*SBLK*SBLK*4); // +8 MiB
  float* out = (float*)d_out;

  pcr_phase1<<<NBLK * 4, THREADS, 0, stream>>>(A, B, v, C, D);
  pcr_phase2<<<(CH_N * SBAT) / 32, 256, 0, stream>>>(C, D, out);
}